// Round 8
// baseline (337.985 us; speedup 1.0000x reference)
//
#include <hip/hip_runtime.h>
#include <hip/hip_bf16.h>
#include <stdint.h>

// WindowAttention: B_=256 windows, N=98 tokens, DIM=768, NH=24, HD=32.
// Round 15 (= round 14 resubmitted after infra failure): bm materialization
// deleted. Attn reads biasA (f32, deduped gather, -1e30-padded [h][112][112],
// L2-resident 1.2 MB) + mask (f32, 2.4 MB L2-resident) directly in the
// softmax -- removes stage-B's 38.5 MB write and ~115 MB of bm HBM re-reads.
// Attn grid reordered so each XCD owns 8 windows with (w, rep, h) adjacency
// -> mask/biasA L2-hot. GEMM pure 3528 blocks (T2 swizzle, head-major
// epilogue). Swapped-QK^T attn core retained.

#define NTOK 98
#define MT 7
#define NPAD 112
#define DIMX 768
#define NHEAD 24
#define HDIM 32
#define NQKV 2304          // 3*DIM
#define BROWS 25088        // 256*98
#define SCALE 0.17677669529663689f
#define LOG2E 1.4426950408889634f
#define SCL2E (SCALE * LOG2E)
#define NN2 (NTOK * NTOK)  // 9604
#define BMROW 112
#define BMSZ (BMROW * BMROW)   // 12544 floats per head (biasA)
#define BMQ (BMSZ / 4)         // 3136 elem4 per head
#define PLANE ((size_t)BROWS * HDIM)   // 802816 elems per (s,h) plane

#define NB_X 18816     // 4816896/256 x-convert blocks
#define NB_W 1728      // 442368/256 w-convert blocks
#define NB_BA 294      // 24*3136/256 biasA blocks
#define GEMM_BLKS 3528 // 196*18

#if __has_builtin(__builtin_amdgcn_exp2f)
#define EXP2F(x) __builtin_amdgcn_exp2f(x)
#else
#define EXP2F(x) exp2f(x)
#endif

typedef __attribute__((ext_vector_type(8))) short short8;
typedef __attribute__((ext_vector_type(4))) short short4v;
typedef __attribute__((ext_vector_type(4))) float floatx4;

__device__ __forceinline__ short f2b(float f) {
    __hip_bfloat16 h = __float2bfloat16(f);
    return __builtin_bit_cast(short, h);
}

__device__ __forceinline__ void gload_lds16(const void* g, void* l) {
    __builtin_amdgcn_global_load_lds(
        (const __attribute__((address_space(1))) void*)g,
        (__attribute__((address_space(3))) void*)l, 16, 0, 0);
}

// biasA[h][112][112] = LOG2E*rel_table[rel_index[i][j]][h]; -1e30 in pads.
__device__ __forceinline__ void biasA_body(int t,
                                           const float* __restrict__ rel_table,
                                           const int* __restrict__ rel_index,
                                           float* __restrict__ biasA) {
    int h = t / BMQ;
    int r4 = t % BMQ;
    int i = r4 / 28, j0 = (r4 % 28) * 4;
    float4 o;
    #pragma unroll
    for (int jj = 0; jj < 4; ++jj) {
        int j = j0 + jj;
        float val = -1e30f;
        if (i < NTOK && j < NTOK)
            val = rel_table[(size_t)rel_index[i * NTOK + j] * NHEAD + h] * LOG2E;
        o[jj] = val;
    }
    ((float4*)biasA)[t] = o;   // t == h*BMQ + r4
}

// ------ merged prep: x-convert | W-perm-convert | biasA gather ------
__global__ void prep_kernel(const float* __restrict__ x,
                            const float* __restrict__ w,
                            const float* __restrict__ rel_table,
                            const int* __restrict__ rel_index,
                            short* __restrict__ xb,
                            short* __restrict__ wb,
                            float* __restrict__ biasA) {
    int bid = blockIdx.x;
    if (bid < NB_X) {
        int i = bid * 256 + threadIdx.x;        // exact: NB_X*256 elements
        float4 f = ((const float4*)x)[i];
        short4v s = { f2b(f.x), f2b(f.y), f2b(f.z), f2b(f.w) };
        ((short4v*)xb)[i] = s;
    } else if (bid < NB_X + NB_W) {
        int i = (bid - NB_X) * 256 + threadIdx.x;   // exact: NB_W*256
        int cp = i / 192, k4 = i % 192;
        int s = cp / DIMX, rem = cp % DIMX;
        int orig = (rem >> 5) * 96 + (rem & 31) * 3 + s;
        float sc = (s == 0) ? SCL2E : 1.0f;
        float4 f = ((const float4*)(w + (size_t)orig * DIMX))[k4];
        short4v o = { f2b(f.x * sc), f2b(f.y * sc), f2b(f.z * sc), f2b(f.w * sc) };
        ((short4v*)(wb + (size_t)cp * DIMX))[k4] = o;
    } else {
        int t = (bid - NB_X - NB_W) * 256 + threadIdx.x;  // exact: NB_BA*256
        biasA_body(t, rel_table, rel_index, biasA);
    }
}

// standalone biasA (mid path: biasA aliases xb region, runs post-GEMM)
__global__ void biasA_kernel(const float* __restrict__ rel_table,
                             const int* __restrict__ rel_index,
                             float* __restrict__ biasA) {
    int t = blockIdx.x * 256 + threadIdx.x;
    if (t >= NHEAD * BMQ) return;
    biasA_body(t, rel_table, rel_index, biasA);
}

// bias_pre[h][i][j] = rel_table[rel_index[i][j]][h]   (fallback path only)
__global__ void bias_gather_kernel(const float* __restrict__ rel_table,
                                   const int* __restrict__ rel_index,
                                   float* __restrict__ bias_pre) {
    int t = blockIdx.x * 256 + threadIdx.x;
    if (t >= NHEAD * NN2) return;
    int h  = t / NN2;
    int ij = t % NN2;
    bias_pre[t] = rel_table[(size_t)rel_index[ij] * NHEAD + h];
}

// ---- GEMM: qkv[s][h][25088][32] = xb @ wb^T + b_perm (pure, 3528 blocks) --
// 128x128 tiles, BK=64, 256 thr (2x2 waves, each 4x4 16x16 MFMA tiles).
// T2 XOR swizzle (bank-conflict-free). XCD swizzle: 3528 = 8*441.
__global__ void gemm_kernel(const short* __restrict__ xb,
                            const short* __restrict__ wb,
                            const float* __restrict__ qkv_b,
                            short* __restrict__ qkv) {
    __shared__ short At[128 * 64];
    __shared__ short Bt[128 * 64];
    const int tid  = threadIdx.x;
    const int lane = tid & 63;
    const int wv   = tid >> 6;
    const int wr   = wv >> 1, wc = wv & 1;
    const int l15  = lane & 15;
    const int l4   = lane >> 4;

    int bid = blockIdx.x;
    int swz = (bid & 7) * 441 + (bid >> 3);
    const int mtile = swz / 18;
    const int ntile = swz % 18;

    const short* aB = xb + (size_t)(mtile * 128) * DIMX;
    const short* bB = wb + (size_t)(ntile * 128) * DIMX;
    const int lrow = lane >> 3;                        // 0..7 == row&7
    const int lcs  = (((lane & 7) ^ lrow) * 8);        // pre-swizzled col (elems)
    const int sa   = (l15 & 7) << 3;                   // read-side XOR (elems)

    floatx4 acc[4][4];
    #pragma unroll
    for (int m = 0; m < 4; ++m)
        #pragma unroll
        for (int n = 0; n < 4; ++n) acc[m][n] = (floatx4){0.f, 0.f, 0.f, 0.f};

    for (int kb = 0; kb < 12; ++kb) {
        #pragma unroll
        for (int j = 0; j < 4; ++j) {
            int r = wv * 32 + j * 8;
            gload_lds16(aB + (size_t)(r + lrow) * DIMX + kb * 64 + lcs, &At[r * 64]);
            gload_lds16(bB + (size_t)(r + lrow) * DIMX + kb * 64 + lcs, &Bt[r * 64]);
        }
        __syncthreads();
        #pragma unroll
        for (int kh = 0; kh < 2; ++kh) {
            int k0 = kh * 32 + l4 * 8;
            int k0s = k0 ^ sa;
            short8 af[4], bfr[4];
            #pragma unroll
            for (int m = 0; m < 4; ++m)
                af[m] = *(const short8*)(&At[(wr * 64 + m * 16 + l15) * 64 + k0s]);
            #pragma unroll
            for (int n = 0; n < 4; ++n)
                bfr[n] = *(const short8*)(&Bt[(wc * 64 + n * 16 + l15) * 64 + k0s]);
            #pragma unroll
            for (int m = 0; m < 4; ++m)
                #pragma unroll
                for (int n = 0; n < 4; ++n)
                    acc[m][n] = __builtin_amdgcn_mfma_f32_16x16x32_bf16(
                        af[m], bfr[n], acc[m][n], 0, 0, 0);
        }
        __syncthreads();
    }

    // Epilogue: head-major store qkv[s][h2][row][d].
    #pragma unroll
    for (int n = 0; n < 4; ++n) {
        int col = ntile * 128 + wc * 64 + n * 16 + l15;
        int s = col / DIMX, rem = col % DIMX;
        int h2 = rem >> 5, d = rem & 31;
        int orig = h2 * 96 + d * 3 + s;
        float bias = qkv_b[orig] * ((s == 0) ? SCL2E : 1.0f);
        short* base = qkv + (size_t)(s * NHEAD + h2) * PLANE + d;
        #pragma unroll
        for (int m = 0; m < 4; ++m) {
            int row0 = mtile * 128 + wr * 64 + m * 16 + l4 * 4;
            #pragma unroll
            for (int r = 0; r < 4; ++r)
                base[(size_t)(row0 + r) * HDIM] = f2b(acc[m][n][r] + bias);
        }
    }
}

// ---------------- Attention per (window b, head h) ----------------
struct __align__(16) SMemC {
    short P[NPAD * 128];   // 28672 B, XOR-swizzled cols
    short q[NPAD * HDIM];  // 7168 B  [tok][d] linear
    short k[NPAD * HDIM];  // 7168 B  [tok][d] linear
    short vt[HDIM * 128];  // 8192 B  [d][tok], XOR-swizzled cols
};                         // 51200 B -> 3 blocks/CU

__global__ __launch_bounds__(256, 3) void attn_kernel6(
    const short* __restrict__ qkv,
    const float* __restrict__ biasA,
    const float* __restrict__ mask,
    float* __restrict__ out) {
    __shared__ SMemC sm;
    const int tid  = threadIdx.x;
    const int lane = tid & 63;
    const int wv   = tid >> 6;
    const int l15  = lane & 15;
    const int l4   = lane >> 4;
    // XCD-local mapping: xcd owns 8 windows; within: (w_local, rep, h)
    // adjacent so mask[w]/biasA slices stay L2-hot and the 4 windows
    // sharing (b&63) are dispatch-adjacent on one XCD.
    int id = blockIdx.x;
    int xcd = id & 7, slot = id >> 3;          // slot in [0,768)
    int w_local = slot / 96;
    int rem = slot % 96;
    int rep = rem / 24;
    const int h = rem % 24;
    int w = xcd * 8 + w_local;                 // [0,64)
    const int b = rep * 64 + w;                // [0,256); b & 63 == w
    // head-major qkv: each slice is 98*32 contiguous elems (6272 B)
    const short* qh = qkv + (size_t)h * PLANE            + (size_t)b * NTOK * HDIM;
    const short* kh = qkv + (size_t)(NHEAD + h) * PLANE  + (size_t)b * NTOK * HDIM;
    const short* vh = qkv + (size_t)(2 * NHEAD + h) * PLANE + (size_t)b * NTOK * HDIM;

    // q,k: contiguous gload_lds, 1024B (16 rows) per call; tail masked.
    #pragma unroll
    for (int it = 0; it < 2; ++it) {
        int row0 = it * 64 + wv * 16;
        if (row0 < NTOK) {
            if (lane < (NTOK - row0) * 4) {   // 4 lanes (64B) per row
                gload_lds16(qh + row0 * HDIM + lane * 8, &sm.q[row0 * HDIM]);
                gload_lds16(kh + row0 * HDIM + lane * 8, &sm.k[row0 * HDIM]);
            }
        }
    }
    // v: transpose-stage, 2 tokens packed per b32 write, swizzled cols
    if (tid < 196) {
        int t = (tid >> 2) * 2, dh = tid & 3;
        const short* vp = vh + t * HDIM + dh * 8;
        short8 va = *(const short8*)vp;
        short8 vb = *(const short8*)(vp + HDIM);
        #pragma unroll
        for (int j = 0; j < 8; ++j) {
            int d = dh * 8 + j;
            int csw = t ^ ((d & 7) << 3);
            unsigned pk = ((unsigned)(unsigned short)vb[j] << 16) |
                          (unsigned)(unsigned short)va[j];
            *(unsigned*)(&sm.vt[d * 128 + csw]) = pk;
        }
    }
    // zero pads: q/k rows 98..111, vt tokens 98..127, P cols 112..127
    if (tid < 112) {
        int a = tid / 56, r2 = (tid % 56) >> 2, seg = (tid & 3) * 8;
        short* dst = (a ? sm.k : sm.q) + (NTOK + r2) * HDIM + seg;
        *(uint4*)dst = (uint4){0u, 0u, 0u, 0u};
    }
    for (int t = tid; t < HDIM * 30; t += 256) {
        int d = t / 30, c = NTOK + t % 30;
        sm.vt[d * 128 + (c ^ ((d & 7) << 3))] = 0;
    }
    for (int t = tid; t < NPAD * 16; t += 256) {
        int r = t >> 4, c = 112 + (t & 15);
        sm.P[r * 128 + (c ^ ((r & 7) << 3))] = 0;
    }
    __syncthreads();

    int mt[2];
    mt[0] = wv;
    mt[1] = (wv + 4 < MT) ? (wv + 4) : wv;

    // Phase 2: S^T = K @ Q^T (swapped operands). Lane holds, for its q-token
    // (col = l15 within the wave's q-tile), k = kt*16 + l4*4 + r.
    floatx4 sacc[2][7];
    #pragma unroll
    for (int i = 0; i < 2; ++i)
        #pragma unroll
        for (int j = 0; j < 7; ++j) sacc[i][j] = (floatx4){0.f, 0.f, 0.f, 0.f};
    {
        int k0 = l4 * 8;
        short8 bq[2];
        #pragma unroll
        for (int iq = 0; iq < 2; ++iq)
            bq[iq] = *(const short8*)(&sm.q[(mt[iq] * 16 + l15) * HDIM + k0]);
        __builtin_amdgcn_s_setprio(1);
        #pragma unroll
        for (int kt = 0; kt < 7; ++kt) {
            short8 ak = *(const short8*)(&sm.k[(kt * 16 + l15) * HDIM + k0]);
            #pragma unroll
            for (int iq = 0; iq < 2; ++iq)
                sacc[iq][kt] = __builtin_amdgcn_mfma_f32_16x16x32_bf16(
                    ak, bq[iq], sacc[iq][kt], 0, 0, 0);
        }
        __builtin_amdgcn_s_setprio(0);
    }

    // Softmax: logits = sacc (pre-scaled) + biasA (pre-scaled, -1e30 pads)
    //                 + LOG2E*mask. biasA pads handle all j/q guards.
    const float* bah = biasA + (size_t)h * BMSZ;   // [112][112] f32
    const float* mw  = mask + (size_t)(b & 63) * NN2;
    const int swzp = (l15 & 7) << 3;   // P-col XOR swizzle (row&7 == l15&7)

    #pragma unroll
    for (int iq = 0; iq < 2; ++iq) {
        int q = mt[iq] * 16 + l15;
        const float* bap = bah + q * BMROW + l4 * 4;
        const float* mp  = mw  + q * NTOK  + l4 * 4;
        bool qv = q < NTOK;
        float vv[7][4];
        #pragma unroll
        for (int kt = 0; kt < 7; ++kt) {
            float4 ba = *(const float4*)(bap + kt * 16);
            float m0 = 0.f, m1 = 0.f, m2 = 0.f, m3 = 0.f;
            if (kt < 6) {
                if (qv) {   // j = kt*16 + l4*4 + r <= 95 < 98: all valid
                    float2 a = *(const float2*)(mp + kt * 16);
                    float2 c = *(const float2*)(mp + kt * 16 + 2);
                    m0 = a.x; m1 = a.y; m2 = c.x; m3 = c.y;
                }
            } else {
                if (qv && l4 == 0) {   // only j=96,97 valid in last tile
                    float2 a = *(const float2*)(mp + 96);
                    m0 = a.x; m1 = a.y;
                }
            }
            vv[kt][0] = sacc[iq][kt][0] + ba.x + m0 * LOG2E;
            vv[kt][1] = sacc[iq][kt][1] + ba.y + m1 * LOG2E;
            vv[kt][2] = sacc[iq][kt][2] + ba.z + m2 * LOG2E;
            vv[kt][3] = sacc[iq][kt][3] + ba.w + m3 * LOG2E;
        }
        float mx = vv[0][0];
        #pragma unroll
        for (int kt = 0; kt < 7; ++kt)
            #pragma unroll
            for (int r = 0; r < 4; ++r) mx = fmaxf(mx, vv[kt][r]);
        mx = fmaxf(mx, __shfl_xor(mx, 16));
        mx = fmaxf(mx, __shfl_xor(mx, 32));
        float s = 0.f;
        #pragma unroll
        for (int kt = 0; kt < 7; ++kt)
            #pragma unroll
            for (int r = 0; r < 4; ++r) {
                float e = EXP2F(vv[kt][r] - mx);   // pads: -1e30 -> 0
                vv[kt][r] = e;
                s += e;
            }
        s += __shfl_xor(s, 16);
        s += __shfl_xor(s, 32);
        float inv = qv ? 1.f / s : 0.f;
        #pragma unroll
        for (int kt = 0; kt < 7; ++kt) {
            short4v pw = { f2b(vv[kt][0] * inv), f2b(vv[kt][1] * inv),
                           f2b(vv[kt][2] * inv), f2b(vv[kt][3] * inv) };
            *(short4v*)(&sm.P[q * 128 + ((kt * 16 + l4 * 4) ^ swzp)]) = pw;
        }
    }
    __syncthreads();

    // Phase 3: O = P(98x128pad) @ V(128x32), swizzled reads
    floatx4 oacc[2][2];
    #pragma unroll
    for (int i = 0; i < 2; ++i)
        #pragma unroll
        for (int j = 0; j < 2; ++j) oacc[i][j] = (floatx4){0.f, 0.f, 0.f, 0.f};

    __builtin_amdgcn_s_setprio(1);
    #pragma unroll
    for (int kt = 0; kt < 4; ++kt) {
        int kk = (kt * 32 + l4 * 8) ^ swzp;
        short8 ap[2];
        #pragma unroll
        for (int im = 0; im < 2; ++im)
            ap[im] = *(const short8*)(&sm.P[(mt[im] * 16 + l15) * 128 + kk]);
        #pragma unroll
        for (int nt = 0; nt < 2; ++nt) {
            short8 bv = *(const short8*)(&sm.vt[(nt * 16 + l15) * 128 + kk]);
            #pragma unroll
            for (int im = 0; im < 2; ++im)
                oacc[im][nt] = __builtin_amdgcn_mfma_f32_16x16x32_bf16(
                    ap[im], bv, oacc[im][nt], 0, 0, 0);
        }
    }
    __builtin_amdgcn_s_setprio(0);

    float* ob = out + (size_t)b * NTOK * DIMX + h * HDIM;
    #pragma unroll
    for (int im = 0; im < 2; ++im)
        #pragma unroll
        for (int nt = 0; nt < 2; ++nt) {
            int dd = nt * 16 + l15;
            #pragma unroll
            for (int r = 0; r < 4; ++r) {
                int tok = mt[im] * 16 + l4 * 4 + r;
                if (tok < NTOK)
                    ob[(size_t)tok * DIMX + dd] = oacc[im][nt][r];
            }
        }
}

// ---------------- Fallback: fused kernel (fp32 in, fp32 out) -------
struct __align__(16) SMemF {
    union {
        struct {
            short xt[NPAD * 64];
            short wt[96 * 64];
        } p1;
        short P[NPAD * 128];
    } u;
    short q[NPAD * HDIM];
    short k[NPAD * HDIM];
    short vt[HDIM * 128];
};

__global__ __launch_bounds__(256, 3) void attn_fused(
    const float* __restrict__ x,
    const float* __restrict__ mask,
    const float* __restrict__ qkv_w,
    const float* __restrict__ qkv_b,
    const float* __restrict__ bias_pre,
    const float* __restrict__ rel_table,
    const int* __restrict__ rel_index,
    float* __restrict__ out) {
    __shared__ SMemF sm;
    const int tid  = threadIdx.x;
    const int lane = tid & 63;
    const int wv   = tid >> 6;
    const int l15  = lane & 15;
    const int l4   = lane >> 4;
    const int b = blockIdx.x / NHEAD;
    const int h = blockIdx.x % NHEAD;
    const float* xp = x + (size_t)b * NTOK * DIMX;
    const float* wp = qkv_w + (size_t)h * 96 * DIMX;
    int mt[2];
    mt[0] = wv;
    mt[1] = (wv + 4 < MT) ? (wv + 4) : wv;

    floatx4 acc[2][6];
    #pragma unroll
    for (int i = 0; i < 2; ++i)
        #pragma unroll
        for (int j = 0; j < 6; ++j) acc[i][j] = (floatx4){0.f, 0.f, 0.f, 0.f};

    for (int kb = 0; kb < 12; ++kb) {
        for (int t = tid; t < NTOK * 16; t += 256) {
            int row = t >> 4, c = t & 15;
            float4 f = *(const float4*)(xp + (size_t)row * DIMX + kb * 64 + c * 4);
            short4v s = { f2b(f.x), f2b(f.y), f2b(f.z), f2b(f.w) };
            *(short4v*)(&sm.u.p1.xt[row * 64 + c * 4]) = s;
        }
        for (int t = tid; t < 96 * 16; t += 256) {
            int row = t >> 4, c = t & 15;
            float4 f = *(const float4*)(wp + (size_t)row * DIMX + kb * 64 + c * 4);
            short4v s = { f2b(f.x), f2b(f.y), f2b(f.z), f2b(f.w) };
            *(short4v*)(&sm.u.p1.wt[row * 64 + c * 4]) = s;
        }
        if (tid < 14 * 8) {
            int row = 98 + (tid >> 3), c = tid & 7;
            uint4 z = {0u, 0u, 0u, 0u};
            *(uint4*)(&sm.u.p1.xt[row * 64 + c * 8]) = z;
        }
        __syncthreads();
        #pragma unroll
        for (int ks = 0; ks < 2; ++ks) {
            int k0 = ks * 32 + l4 * 8;
            short8 aM[2];
            #pragma unroll
            for (int im = 0; im < 2; ++im)
                aM[im] = *(const short8*)(&sm.u.p1.xt[(mt[im] * 16 + l15) * 64 + k0]);
            #pragma unroll
            for (int nt = 0; nt < 6; ++nt) {
                short8 bN = *(const short8*)(&sm.u.p1.wt[(nt * 16 + l15) * 64 + k0]);
                #pragma unroll
                for (int im = 0; im < 2; ++im)
                    acc[im][nt] = __builtin_amdgcn_mfma_f32_16x16x32_bf16(
                        aM[im], bN, acc[im][nt], 0, 0, 0);
            }
        }
        __syncthreads();
    }

    #pragma unroll
    for (int im = 0; im < 2; ++im)
        #pragma unroll
        for (int nt = 0; nt < 6; ++nt) {
            int col = nt * 16 + l15;
            int d = col / 3, s = col % 3;
            float bias = qkv_b[h * 96 + col];
            #pragma unroll
            for (int r = 0; r < 4; ++r) {
                int tok = mt[im] * 16 + l4 * 4 + r;
                short val = f2b(acc[im][nt][r] + bias);
                if (s == 0)      sm.q[tok * HDIM + d] = val;
                else if (s == 1) sm.k[tok * HDIM + d] = val;
                else             sm.vt[d * 128 + tok] = val;
            }
        }
    __syncthreads();
    for (int t = tid; t < HDIM * 30; t += 256) {
        int d = t / 30, c = 98 + t % 30;
        sm.vt[d * 128 + c] = 0;
    }
    for (int t = tid; t < NPAD * 16; t += 256) {
        int row = t >> 4, c = 112 + (t & 15);
        sm.u.P[row * 128 + c] = 0;
    }

    floatx4 sacc[2][7];
    #pragma unroll
    for (int i = 0; i < 2; ++i)
        #pragma unroll
        for (int j = 0; j < 7; ++j) sacc[i][j] = (floatx4){0.f, 0.f, 0.f, 0.f};
    {
        int k0 = l4 * 8;
        short8 aq[2];
        #pragma unroll
        for (int im = 0; im < 2; ++im)
            aq[im] = *(const short8*)(&sm.q[(mt[im] * 16 + l15) * HDIM + k0]);
        #pragma unroll
        for (int nt = 0; nt < 7; ++nt) {
            short8 bk = *(const short8*)(&sm.k[(nt * 16 + l15) * HDIM + k0]);
            #pragma unroll
            for (int im = 0; im < 2; ++im)
                sacc[im][nt] = __builtin_amdgcn_mfma_f32_16x16x32_bf16(
                    aq[im], bk, sacc[im][nt], 0, 0, 0);
        }
    }

    const float* biash = bias_pre ? (bias_pre + (size_t)h * NN2) : nullptr;
    const size_t moff = (size_t)(b & 63) * NN2;

    #pragma unroll
    for (int im = 0; im < 2; ++im)
        #pragma unroll
        for (int r = 0; r < 4; ++r) {
            int row = mt[im] * 16 + l4 * 4 + r;
            bool vrow = row < NTOK;
            float v[7];
            #pragma unroll
            for (int nt = 0; nt < 7; ++nt) {
                int j = nt * 16 + l15;
                bool vj = vrow && (j < NTOK);
                float bmv = 0.f;
                if (vj) {
                    float bias = biash ? biash[row * NTOK + j]
                        : rel_table[(size_t)rel_index[row * NTOK + j] * NHEAD + h];
                    bmv = bias + mask[moff + row * NTOK + j];
                }
                v[nt] = vj ? sacc[im][nt][r] * SCALE + bmv : -1e30f;
            }
            float mx = v[0];
            #pragma unroll
            for (int nt = 1; nt < 7; ++nt) mx = fmaxf(mx, v[nt]);
            #pragma unroll
            for (int off = 1; off < 16; off <<= 1) mx = fmaxf(mx, __shfl_xor(mx, off));
            float s = 0.f;
            #pragma unroll
            for (int nt = 0; nt < 7; ++nt) {
                float e = (v[nt] > -1e29f) ? __expf(v[nt] - mx) : 0.f;
                v[nt] = e;
                s += e;
            }
            #pragma unroll
            for (int off = 1; off < 16; off <<= 1) s += __shfl_xor(s, off);
            float inv = vrow ? 1.f / s : 0.f;
            #pragma unroll
            for (int nt = 0; nt < 7; ++nt)
                sm.u.P[row * 128 + nt * 16 + l15] = f2b(v[nt] * inv);
        }
    __syncthreads();

    floatx4 oacc[2][2];
    #pragma unroll
    for (int i = 0; i < 2; ++i)
        #pragma unroll
        for (int j = 0; j < 2; ++j) oacc[i][j] = (floatx4){0.f, 0.f, 0.f, 0.f};
    #pragma unroll
    for (int kt = 0; kt < 4; ++kt) {
        int kk = kt * 32 + l4 * 8;
        short8 ap[2];
        #pragma unroll
        for (int im = 0; im < 2; ++im)
            ap[im] = *(const short8*)(&sm.u.P[(mt[im] * 16 + l15) * 128 + kk]);
        #pragma unroll
        for (int nt = 0; nt < 2; ++nt) {
            short8 bv = *(const short8*)(&sm.vt[(nt * 16 + l15) * 128 + kk]);
            #pragma unroll
            for (int im = 0; im < 2; ++im)
                oacc[im][nt] = __builtin_amdgcn_mfma_f32_16x16x32_bf16(
                    ap[im], bv, oacc[im][nt], 0, 0, 0);
        }
    }
    float* ob = out + (size_t)b * NTOK * DIMX + h * HDIM;
    #pragma unroll
    for (int im = 0; im < 2; ++im)
        #pragma unroll
        for (int nt = 0; nt < 2; ++nt) {
            int dd = nt * 16 + l15;
            #pragma unroll
            for (int r = 0; r < 4; ++r) {
                int tok = mt[im] * 16 + l4 * 4 + r;
                if (tok < NTOK)
                    ob[(size_t)tok * DIMX + dd] = oacc[im][nt][r];
            }
        }
}

extern "C" void kernel_launch(void* const* d_in, const int* in_sizes, int n_in,
                              void* d_out, int out_size, void* d_ws, size_t ws_size,
                              hipStream_t stream) {
    const float* x = (const float*)d_in[0];
    const float* mask = (const float*)d_in[1];
    const float* qkv_w = (const float*)d_in[2];
    const float* qkv_b = (const float*)d_in[3];
    const float* rel_table = (const float*)d_in[4];
    const int* rel_index = (const int*)d_in[5];
    for (int i = 0; i < n_in; ++i) {
        switch (in_sizes[i]) {
            case 256 * NTOK * DIMX:  x         = (const float*)d_in[i]; break;
            case 64 * NN2:           mask      = (const float*)d_in[i]; break;
            case 3 * DIMX * DIMX:    qkv_w     = (const float*)d_in[i]; break;
            case 3 * DIMX:           qkv_b     = (const float*)d_in[i]; break;
            case 507 * NHEAD:        rel_table = (const float*)d_in[i]; break;
            case NN2:                rel_index = (const int*)d_in[i]; break;
            default: break;
        }
    }
    float* out = (float*)d_out;

    const size_t xb_bytes    = (size_t)BROWS * DIMX * 2;      // 38535168
    const size_t wb_bytes    = (size_t)NQKV * DIMX * 2;       // 3538944
    const size_t qkv_bytes   = (size_t)BROWS * NQKV * 2;      // 115605504
    const size_t biasA_bytes = (size_t)NHEAD * BMSZ * 4;      // 1204224
    const size_t total       = xb_bytes + wb_bytes + qkv_bytes;

    if (ws_size >= total + biasA_bytes) {
        // preferred: biasA in its own region, gathered during prep
        short* xb    = (short*)d_ws;
        short* wb    = (short*)((char*)d_ws + xb_bytes);
        short* qkv   = (short*)((char*)d_ws + xb_bytes + wb_bytes);
        float* biasA = (float*)((char*)d_ws + total);

        prep_kernel<<<NB_X + NB_W + NB_BA, 256, 0, stream>>>(
            x, qkv_w, rel_table, rel_index, xb, wb, biasA);
        gemm_kernel<<<GEMM_BLKS, 256, 0, stream>>>(xb, wb, qkv_b, qkv);
        attn_kernel6<<<256 * NHEAD, 256, 0, stream>>>(qkv, biasA, mask, out);
    } else if (ws_size >= total) {
        // mid path: biasA aliases the (dead after gemm) xb region
        short* xb    = (short*)d_ws;
        short* wb    = (short*)((char*)d_ws + xb_bytes);
        short* qkv   = (short*)((char*)d_ws + xb_bytes + wb_bytes);
        float* biasA = (float*)d_ws;

        prep_kernel<<<NB_X + NB_W, 256, 0, stream>>>(
            x, qkv_w, rel_table, rel_index, xb, wb, nullptr);
        gemm_kernel<<<GEMM_BLKS, 256, 0, stream>>>(xb, wb, qkv_b, qkv);
        biasA_kernel<<<NB_BA, 256, 0, stream>>>(rel_table, rel_index, biasA);
        attn_kernel6<<<256 * NHEAD, 256, 0, stream>>>(qkv, biasA, mask, out);
    } else {
        const size_t bias_bytes = (size_t)NHEAD * NN2 * sizeof(float);
        float* bias_pre = (ws_size >= bias_bytes) ? (float*)d_ws : nullptr;
        if (bias_pre) {
            int nb = NHEAD * NN2;
            bias_gather_kernel<<<(nb + 255) / 256, 256, 0, stream>>>(rel_table, rel_index, bias_pre);
        }
        attn_fused<<<256 * NHEAD, 256, 0, stream>>>(x, mask, qkv_w, qkv_b,
                                                    bias_pre, rel_table, rel_index, out);
    }
}

// Round 9
// 305.277 us; speedup vs baseline: 1.1071x; 1.1071x over previous
//
#include <hip/hip_runtime.h>
#include <hip/hip_bf16.h>
#include <stdint.h>

// WindowAttention: B_=256 windows, N=98 tokens, DIM=768, NH=24, HD=32.
// Round 16: revert round-8's direct bias/mask softmax reads (regression:
// 40 scattered f32 loads/thread vs 14x8B bm loads; attn 72->106 us) back to
// the round-6 two-stage materialized bm. NEW: attn LDS phase-union --
// q/k (dead after QK^T) share storage with P (born after) -> 36864 B,
// 4 blocks/CU (was 51200 B / 3), one extra barrier between QK^T and
// softmax P-stores. gemm keeps T2 swizzle + head-major epilogue + stage-B
// bm rider (proven 110 us).

#define NTOK 98
#define MT 7
#define NPAD 112
#define DIMX 768
#define NHEAD 24
#define HDIM 32
#define NQKV 2304          // 3*DIM
#define BROWS 25088        // 256*98
#define SCALE 0.17677669529663689f
#define LOG2E 1.4426950408889634f
#define SCL2E (SCALE * LOG2E)
#define NN2 (NTOK * NTOK)  // 9604
#define BMROW 112
#define BMSZ (BMROW * BMROW)   // 12544 per (w,h)
#define BMQ (BMSZ / 4)         // 3136 elem4 per (w,h)
#define PLANE ((size_t)BROWS * HDIM)   // 802816 elems per (s,h) plane

#define NB_X 18816     // 4816896/256 x-convert blocks
#define NB_W 1728      // 442368/256 w-convert blocks
#define NB_BA 294      // 24*3136/256 stage-A blocks
#define NB_B2 2352     // stage-B blocks (x8 grid-stride = 4816896 elem4)
#define GEMM_BLKS 3528 // 196*18

#if __has_builtin(__builtin_amdgcn_exp2f)
#define EXP2F(x) __builtin_amdgcn_exp2f(x)
#else
#define EXP2F(x) exp2f(x)
#endif

typedef __attribute__((ext_vector_type(8))) short short8;
typedef __attribute__((ext_vector_type(4))) short short4v;
typedef __attribute__((ext_vector_type(4))) float floatx4;

__device__ __forceinline__ short f2b(float f) {
    __hip_bfloat16 h = __float2bfloat16(f);
    return __builtin_bit_cast(short, h);
}
__device__ __forceinline__ float b2f(unsigned short s) {
    return __builtin_bit_cast(float, ((unsigned)s) << 16);
}

__device__ __forceinline__ void gload_lds16(const void* g, void* l) {
    __builtin_amdgcn_global_load_lds(
        (const __attribute__((address_space(1))) void*)g,
        (__attribute__((address_space(3))) void*)l, 16, 0, 0);
}

// full-gather bm (alias fallback path only; runs serial post-GEMM)
__device__ __forceinline__ void bm_body(int t,
                                        const float* __restrict__ rel_table,
                                        const int* __restrict__ rel_index,
                                        const float* __restrict__ mask,
                                        short* __restrict__ bm) {
    int wh = t / BMQ;
    int r4 = t % BMQ;
    int i = r4 / 28;
    int j0 = (r4 % 28) * 4;
    int h = wh % NHEAD, w = wh / NHEAD;
    short4v o;
    #pragma unroll
    for (int jj = 0; jj < 4; ++jj) {
        int j = j0 + jj;
        float val = -1e30f;
        if (i < NTOK && j < NTOK) {
            float bv = rel_table[(size_t)rel_index[i * NTOK + j] * NHEAD + h];
            float mv = mask[(size_t)w * NN2 + i * NTOK + j];
            val = (bv + mv) * LOG2E;
        }
        o[jj] = f2b(val);
    }
    *(short4v*)(bm + (size_t)wh * BMSZ + i * BMROW + j0) = o;
}

// ------ merged prep: x-convert | W-perm-convert | stage-A bias gather ------
__global__ void prep_kernel(const float* __restrict__ x,
                            const float* __restrict__ w,
                            const float* __restrict__ rel_table,
                            const int* __restrict__ rel_index,
                            short* __restrict__ xb,
                            short* __restrict__ wb,
                            float* __restrict__ biasA) {
    int bid = blockIdx.x;
    if (bid < NB_X) {
        int i = bid * 256 + threadIdx.x;        // exact: NB_X*256 elements
        float4 f = ((const float4*)x)[i];
        short4v s = { f2b(f.x), f2b(f.y), f2b(f.z), f2b(f.w) };
        ((short4v*)xb)[i] = s;
    } else if (bid < NB_X + NB_W) {
        int i = (bid - NB_X) * 256 + threadIdx.x;   // exact: NB_W*256
        int cp = i / 192, k4 = i % 192;
        int s = cp / DIMX, rem = cp % DIMX;
        int orig = (rem >> 5) * 96 + (rem & 31) * 3 + s;
        float sc = (s == 0) ? SCL2E : 1.0f;
        float4 f = ((const float4*)(w + (size_t)orig * DIMX))[k4];
        short4v o = { f2b(f.x * sc), f2b(f.y * sc), f2b(f.z * sc), f2b(f.w * sc) };
        ((short4v*)(wb + (size_t)cp * DIMX))[k4] = o;
    } else {
        // stage A: biasA[h][112][112] = LOG2E*rel_table[rel_index[i][j]][h]
        int t = (bid - NB_X - NB_W) * 256 + threadIdx.x;  // exact: NB_BA*256
        int h = t / BMQ;
        int r4 = t % BMQ;
        int i = r4 / 28, j0 = (r4 % 28) * 4;
        float4 o;
        #pragma unroll
        for (int jj = 0; jj < 4; ++jj) {
            int j = j0 + jj;
            float val = -1e30f;
            if (i < NTOK && j < NTOK)
                val = rel_table[(size_t)rel_index[i * NTOK + j] * NHEAD + h] * LOG2E;
            o[jj] = val;
        }
        ((float4*)biasA)[t] = o;   // t == h*BMQ + r4
    }
}

// standalone bm (alias path: bm reuses xb region, must run post-GEMM)
__global__ void bm_kernel(const float* __restrict__ rel_table,
                          const int* __restrict__ rel_index,
                          const float* __restrict__ mask,
                          short* __restrict__ bm) {
    int t = blockIdx.x * 256 + threadIdx.x;
    if (t >= 64 * NHEAD * BMQ) return;
    bm_body(t, rel_table, rel_index, mask, bm);
}

// bias_pre[h][i][j] = rel_table[rel_index[i][j]][h]   (fallback path only)
__global__ void bias_gather_kernel(const float* __restrict__ rel_table,
                                   const int* __restrict__ rel_index,
                                   float* __restrict__ bias_pre) {
    int t = blockIdx.x * 256 + threadIdx.x;
    if (t >= NHEAD * NN2) return;
    int h  = t / NN2;
    int ij = t % NN2;
    bias_pre[t] = rel_table[(size_t)rel_index[ij] * NHEAD + h];
}

// -- GEMM: qkv[s][h][25088][32] = xb @ wb^T + b_perm  (+ stage-B bm blocks) --
// 128x128 tiles, BK=64, 256 thr (2x2 waves, each 4x4 16x16 MFMA tiles).
// T2 XOR swizzle (bank-conflict-free). Blocks >= GEMM_BLKS run stage B:
// bm = bf16(biasA + LOG2E*mask) -- pure streaming, hides under gemm compute.
// XCD swizzle on the gemm range: 3528 = 8*441.
__global__ void gemm_kernel(const short* __restrict__ xb,
                            const short* __restrict__ wb,
                            const float* __restrict__ qkv_b,
                            short* __restrict__ qkv,
                            const float* __restrict__ biasA,
                            const float* __restrict__ mask,
                            short* __restrict__ bm) {
    if (blockIdx.x >= GEMM_BLKS) {
        int base = (blockIdx.x - GEMM_BLKS) * 256 + threadIdx.x;
        #pragma unroll
        for (int it = 0; it < 8; ++it) {
            int t = base + it * (NB_B2 * 256);     // < 64*24*BMQ exactly
            int wh = t / BMQ;
            int r4 = t % BMQ;
            int i = r4 / 28, j0 = (r4 % 28) * 4;
            int h = wh % NHEAD, w = wh / NHEAD;
            float4 ba = ((const float4*)biasA)[h * BMQ + r4];
            float m0 = 0.f, m1 = 0.f, m2 = 0.f, m3 = 0.f;
            if (i < NTOK && j0 < NTOK) {
                const float* mrow = mask + (size_t)w * NN2 + i * NTOK + j0;
                float2 a = *(const float2*)mrow;
                m0 = a.x; m1 = a.y;
                if (j0 < 96) {
                    float2 c = *(const float2*)(mrow + 2);
                    m2 = c.x; m3 = c.y;
                }
            }
            short4v o = { f2b(ba.x + m0 * LOG2E), f2b(ba.y + m1 * LOG2E),
                          f2b(ba.z + m2 * LOG2E), f2b(ba.w + m3 * LOG2E) };
            ((short4v*)bm)[t] = o;
        }
        return;
    }
    __shared__ short At[128 * 64];
    __shared__ short Bt[128 * 64];
    const int tid  = threadIdx.x;
    const int lane = tid & 63;
    const int wv   = tid >> 6;
    const int wr   = wv >> 1, wc = wv & 1;
    const int l15  = lane & 15;
    const int l4   = lane >> 4;

    int bid = blockIdx.x;
    int swz = (bid & 7) * 441 + (bid >> 3);
    const int mtile = swz / 18;
    const int ntile = swz % 18;

    const short* aB = xb + (size_t)(mtile * 128) * DIMX;
    const short* bB = wb + (size_t)(ntile * 128) * DIMX;
    const int lrow = lane >> 3;                        // 0..7 == row&7
    const int lcs  = (((lane & 7) ^ lrow) * 8);        // pre-swizzled col (elems)
    const int sa   = (l15 & 7) << 3;                   // read-side XOR (elems)

    floatx4 acc[4][4];
    #pragma unroll
    for (int m = 0; m < 4; ++m)
        #pragma unroll
        for (int n = 0; n < 4; ++n) acc[m][n] = (floatx4){0.f, 0.f, 0.f, 0.f};

    for (int kb = 0; kb < 12; ++kb) {
        #pragma unroll
        for (int j = 0; j < 4; ++j) {
            int r = wv * 32 + j * 8;
            gload_lds16(aB + (size_t)(r + lrow) * DIMX + kb * 64 + lcs, &At[r * 64]);
            gload_lds16(bB + (size_t)(r + lrow) * DIMX + kb * 64 + lcs, &Bt[r * 64]);
        }
        __syncthreads();
        #pragma unroll
        for (int kh = 0; kh < 2; ++kh) {
            int k0 = kh * 32 + l4 * 8;
            int k0s = k0 ^ sa;
            short8 af[4], bfr[4];
            #pragma unroll
            for (int m = 0; m < 4; ++m)
                af[m] = *(const short8*)(&At[(wr * 64 + m * 16 + l15) * 64 + k0s]);
            #pragma unroll
            for (int n = 0; n < 4; ++n)
                bfr[n] = *(const short8*)(&Bt[(wc * 64 + n * 16 + l15) * 64 + k0s]);
            #pragma unroll
            for (int m = 0; m < 4; ++m)
                #pragma unroll
                for (int n = 0; n < 4; ++n)
                    acc[m][n] = __builtin_amdgcn_mfma_f32_16x16x32_bf16(
                        af[m], bfr[n], acc[m][n], 0, 0, 0);
        }
        __syncthreads();
    }

    // Epilogue: head-major store qkv[s][h2][row][d].
    #pragma unroll
    for (int n = 0; n < 4; ++n) {
        int col = ntile * 128 + wc * 64 + n * 16 + l15;
        int s = col / DIMX, rem = col % DIMX;
        int h2 = rem >> 5, d = rem & 31;
        int orig = h2 * 96 + d * 3 + s;
        float bias = qkv_b[orig] * ((s == 0) ? SCL2E : 1.0f);
        short* base = qkv + (size_t)(s * NHEAD + h2) * PLANE + d;
        #pragma unroll
        for (int m = 0; m < 4; ++m) {
            int row0 = mtile * 128 + wr * 64 + m * 16 + l4 * 4;
            #pragma unroll
            for (int r = 0; r < 4; ++r)
                base[(size_t)(row0 + r) * HDIM] = f2b(acc[m][n][r] + bias);
        }
    }
}

// ---------------- Attention per (window b, head h) ----------------
// Phase-union LDS: q/k live only until QK^T; P lives only after. 36864 B
// -> 4 blocks/CU (was 51200/3). Extra barrier separates the two lifetimes.
struct __align__(16) SMemU {
    short vt[HDIM * 128];          // 8192 B, persistent, XOR-swizzled cols
    union {
        struct {
            short q[NPAD * HDIM];  // 7168 B [tok][d] linear
            short k[NPAD * HDIM];  // 7168 B [tok][d] linear
        } qk;
        short P[NPAD * 128];       // 28672 B, XOR-swizzled cols
    } u;
};                                 // 36864 B

__global__ __launch_bounds__(256, 4) void attn_kernel7(
    const short* __restrict__ qkv,
    const short* __restrict__ bm,
    float* __restrict__ out) {
    __shared__ SMemU sm;
    const int tid  = threadIdx.x;
    const int lane = tid & 63;
    const int wv   = tid >> 6;
    const int l15  = lane & 15;
    const int l4   = lane >> 4;
    int id = blockIdx.x;
    int nb = (id & 7) * 768 + (id >> 3);   // XCD swizzle: 6144 = 8*768
    const int b = nb / NHEAD;
    const int h = nb % NHEAD;
    // head-major qkv: each slice is 98*32 contiguous elems (6272 B)
    const short* qh = qkv + (size_t)h * PLANE            + (size_t)b * NTOK * HDIM;
    const short* kh = qkv + (size_t)(NHEAD + h) * PLANE  + (size_t)b * NTOK * HDIM;
    const short* vh = qkv + (size_t)(2 * NHEAD + h) * PLANE + (size_t)b * NTOK * HDIM;

    // q,k: contiguous gload_lds, 1024B (16 rows) per call; tail masked.
    #pragma unroll
    for (int it = 0; it < 2; ++it) {
        int row0 = it * 64 + wv * 16;
        if (row0 < NTOK) {
            if (lane < (NTOK - row0) * 4) {   // 4 lanes (64B) per row
                gload_lds16(qh + row0 * HDIM + lane * 8, &sm.u.qk.q[row0 * HDIM]);
                gload_lds16(kh + row0 * HDIM + lane * 8, &sm.u.qk.k[row0 * HDIM]);
            }
        }
    }
    // v: transpose-stage, 2 tokens packed per b32 write, swizzled cols
    if (tid < 196) {
        int t = (tid >> 2) * 2, dh = tid & 3;
        const short* vp = vh + t * HDIM + dh * 8;
        short8 va = *(const short8*)vp;
        short8 vb = *(const short8*)(vp + HDIM);
        #pragma unroll
        for (int j = 0; j < 8; ++j) {
            int d = dh * 8 + j;
            int csw = t ^ ((d & 7) << 3);
            unsigned pk = ((unsigned)(unsigned short)vb[j] << 16) |
                          (unsigned)(unsigned short)va[j];
            *(unsigned*)(&sm.vt[d * 128 + csw]) = pk;
        }
    }
    // zero pads: q/k rows 98..111, vt tokens 98..127 (P pads move later)
    if (tid < 112) {
        int a = tid / 56, r2 = (tid % 56) >> 2, seg = (tid & 3) * 8;
        short* dst = (a ? sm.u.qk.k : sm.u.qk.q) + (NTOK + r2) * HDIM + seg;
        *(uint4*)dst = (uint4){0u, 0u, 0u, 0u};
    }
    for (int t = tid; t < HDIM * 30; t += 256) {
        int d = t / 30, c = NTOK + t % 30;
        sm.vt[d * 128 + (c ^ ((d & 7) << 3))] = 0;
    }
    __syncthreads();

    int mt[2];
    mt[0] = wv;
    mt[1] = (wv + 4 < MT) ? (wv + 4) : wv;

    // Phase 2: S^T = K @ Q^T (swapped operands). Lane holds, for its q-token
    // (col = l15 within the wave's q-tile), k = kt*16 + l4*4 + r.
    floatx4 sacc[2][7];
    #pragma unroll
    for (int i = 0; i < 2; ++i)
        #pragma unroll
        for (int j = 0; j < 7; ++j) sacc[i][j] = (floatx4){0.f, 0.f, 0.f, 0.f};
    {
        int k0 = l4 * 8;
        short8 bq[2];
        #pragma unroll
        for (int iq = 0; iq < 2; ++iq)
            bq[iq] = *(const short8*)(&sm.u.qk.q[(mt[iq] * 16 + l15) * HDIM + k0]);
        __builtin_amdgcn_s_setprio(1);
        #pragma unroll
        for (int kt = 0; kt < 7; ++kt) {
            short8 ak = *(const short8*)(&sm.u.qk.k[(kt * 16 + l15) * HDIM + k0]);
            #pragma unroll
            for (int iq = 0; iq < 2; ++iq)
                sacc[iq][kt] = __builtin_amdgcn_mfma_f32_16x16x32_bf16(
                    ak, bq[iq], sacc[iq][kt], 0, 0, 0);
        }
        __builtin_amdgcn_s_setprio(0);
    }

    // q/k lifetimes end here; P may now overwrite the union region.
    __syncthreads();

    // P pad cols 112..127 (swizzled), disjoint from softmax's cols 0..111
    for (int t = tid; t < NPAD * 16; t += 256) {
        int r = t >> 4, c = 112 + (t & 15);
        sm.u.P[r * 128 + (c ^ ((r & 7) << 3))] = 0;
    }

    const short* bmh = bm + ((size_t)(b & 63) * NHEAD + h) * BMSZ;
    const int swzp = (l15 & 7) << 3;   // P-col XOR swizzle (row&7 == l15&7)

    #pragma unroll
    for (int iq = 0; iq < 2; ++iq) {
        int q = mt[iq] * 16 + l15;
        const short* bmq = bmh + q * BMROW + l4 * 4;
        float vv[7][4];
        #pragma unroll
        for (int kt = 0; kt < 7; ++kt) {
            short4v bm4 = *(const short4v*)(bmq + kt * 16);
            #pragma unroll
            for (int r = 0; r < 4; ++r)
                vv[kt][r] = sacc[iq][kt][r] + b2f((unsigned short)bm4[r]);
        }
        float mx = vv[0][0];
        #pragma unroll
        for (int kt = 0; kt < 7; ++kt)
            #pragma unroll
            for (int r = 0; r < 4; ++r) mx = fmaxf(mx, vv[kt][r]);
        mx = fmaxf(mx, __shfl_xor(mx, 16));
        mx = fmaxf(mx, __shfl_xor(mx, 32));
        float s = 0.f;
        #pragma unroll
        for (int kt = 0; kt < 7; ++kt)
            #pragma unroll
            for (int r = 0; r < 4; ++r) {
                float e = EXP2F(vv[kt][r] - mx);   // pads: -1e30 -> 0
                vv[kt][r] = e;
                s += e;
            }
        s += __shfl_xor(s, 16);
        s += __shfl_xor(s, 32);
        float inv = (q < NTOK) ? 1.f / s : 0.f;
        #pragma unroll
        for (int kt = 0; kt < 7; ++kt) {
            short4v pw = { f2b(vv[kt][0] * inv), f2b(vv[kt][1] * inv),
                           f2b(vv[kt][2] * inv), f2b(vv[kt][3] * inv) };
            *(short4v*)(&sm.u.P[q * 128 + ((kt * 16 + l4 * 4) ^ swzp)]) = pw;
        }
    }
    __syncthreads();

    // Phase 3: O = P(98x128pad) @ V(128x32), swizzled reads
    floatx4 oacc[2][2];
    #pragma unroll
    for (int i = 0; i < 2; ++i)
        #pragma unroll
        for (int j = 0; j < 2; ++j) oacc[i][j] = (floatx4){0.f, 0.f, 0.f, 0.f};

    __builtin_amdgcn_s_setprio(1);
    #pragma unroll
    for (int kt = 0; kt < 4; ++kt) {
        int kk = (kt * 32 + l4 * 8) ^ swzp;
        short8 ap[2];
        #pragma unroll
        for (int im = 0; im < 2; ++im)
            ap[im] = *(const short8*)(&sm.u.P[(mt[im] * 16 + l15) * 128 + kk]);
        #pragma unroll
        for (int nt = 0; nt < 2; ++nt) {
            short8 bv = *(const short8*)(&sm.vt[(nt * 16 + l15) * 128 + kk]);
            #pragma unroll
            for (int im = 0; im < 2; ++im)
                oacc[im][nt] = __builtin_amdgcn_mfma_f32_16x16x32_bf16(
                    ap[im], bv, oacc[im][nt], 0, 0, 0);
        }
    }
    __builtin_amdgcn_s_setprio(0);

    float* ob = out + (size_t)b * NTOK * DIMX + h * HDIM;
    #pragma unroll
    for (int im = 0; im < 2; ++im)
        #pragma unroll
        for (int nt = 0; nt < 2; ++nt) {
            int dd = nt * 16 + l15;
            #pragma unroll
            for (int r = 0; r < 4; ++r) {
                int tok = mt[im] * 16 + l4 * 4 + r;
                if (tok < NTOK)
                    ob[(size_t)tok * DIMX + dd] = oacc[im][nt][r];
            }
        }
}

// ---------------- Fallback: fused kernel (fp32 in, fp32 out) -------
struct __align__(16) SMemF {
    union {
        struct {
            short xt[NPAD * 64];
            short wt[96 * 64];
        } p1;
        short P[NPAD * 128];
    } u;
    short q[NPAD * HDIM];
    short k[NPAD * HDIM];
    short vt[HDIM * 128];
};

__global__ __launch_bounds__(256, 3) void attn_fused(
    const float* __restrict__ x,
    const float* __restrict__ mask,
    const float* __restrict__ qkv_w,
    const float* __restrict__ qkv_b,
    const float* __restrict__ bias_pre,
    const float* __restrict__ rel_table,
    const int* __restrict__ rel_index,
    float* __restrict__ out) {
    __shared__ SMemF sm;
    const int tid  = threadIdx.x;
    const int lane = tid & 63;
    const int wv   = tid >> 6;
    const int l15  = lane & 15;
    const int l4   = lane >> 4;
    const int b = blockIdx.x / NHEAD;
    const int h = blockIdx.x % NHEAD;
    const float* xp = x + (size_t)b * NTOK * DIMX;
    const float* wp = qkv_w + (size_t)h * 96 * DIMX;
    int mt[2];
    mt[0] = wv;
    mt[1] = (wv + 4 < MT) ? (wv + 4) : wv;

    floatx4 acc[2][6];
    #pragma unroll
    for (int i = 0; i < 2; ++i)
        #pragma unroll
        for (int j = 0; j < 6; ++j) acc[i][j] = (floatx4){0.f, 0.f, 0.f, 0.f};

    for (int kb = 0; kb < 12; ++kb) {
        for (int t = tid; t < NTOK * 16; t += 256) {
            int row = t >> 4, c = t & 15;
            float4 f = *(const float4*)(xp + (size_t)row * DIMX + kb * 64 + c * 4);
            short4v s = { f2b(f.x), f2b(f.y), f2b(f.z), f2b(f.w) };
            *(short4v*)(&sm.u.p1.xt[row * 64 + c * 4]) = s;
        }
        for (int t = tid; t < 96 * 16; t += 256) {
            int row = t >> 4, c = t & 15;
            float4 f = *(const float4*)(wp + (size_t)row * DIMX + kb * 64 + c * 4);
            short4v s = { f2b(f.x), f2b(f.y), f2b(f.z), f2b(f.w) };
            *(short4v*)(&sm.u.p1.wt[row * 64 + c * 4]) = s;
        }
        if (tid < 14 * 8) {
            int row = 98 + (tid >> 3), c = tid & 7;
            uint4 z = {0u, 0u, 0u, 0u};
            *(uint4*)(&sm.u.p1.xt[row * 64 + c * 8]) = z;
        }
        __syncthreads();
        #pragma unroll
        for (int ks = 0; ks < 2; ++ks) {
            int k0 = ks * 32 + l4 * 8;
            short8 aM[2];
            #pragma unroll
            for (int im = 0; im < 2; ++im)
                aM[im] = *(const short8*)(&sm.u.p1.xt[(mt[im] * 16 + l15) * 64 + k0]);
            #pragma unroll
            for (int nt = 0; nt < 6; ++nt) {
                short8 bN = *(const short8*)(&sm.u.p1.wt[(nt * 16 + l15) * 64 + k0]);
                #pragma unroll
                for (int im = 0; im < 2; ++im)
                    acc[im][nt] = __builtin_amdgcn_mfma_f32_16x16x32_bf16(
                        aM[im], bN, acc[im][nt], 0, 0, 0);
            }
        }
        __syncthreads();
    }

    #pragma unroll
    for (int im = 0; im < 2; ++im)
        #pragma unroll
        for (int nt = 0; nt < 6; ++nt) {
            int col = nt * 16 + l15;
            int d = col / 3, s = col % 3;
            float bias = qkv_b[h * 96 + col];
            #pragma unroll
            for (int r = 0; r < 4; ++r) {
                int tok = mt[im] * 16 + l4 * 4 + r;
                short val = f2b(acc[im][nt][r] + bias);
                if (s == 0)      sm.q[tok * HDIM + d] = val;
                else if (s == 1) sm.k[tok * HDIM + d] = val;
                else             sm.vt[d * 128 + tok] = val;
            }
        }
    __syncthreads();
    for (int t = tid; t < HDIM * 30; t += 256) {
        int d = t / 30, c = 98 + t % 30;
        sm.vt[d * 128 + c] = 0;
    }
    for (int t = tid; t < NPAD * 16; t += 256) {
        int row = t >> 4, c = 112 + (t & 15);
        sm.u.P[row * 128 + c] = 0;
    }

    floatx4 sacc[2][7];
    #pragma unroll
    for (int i = 0; i < 2; ++i)
        #pragma unroll
        for (int j = 0; j < 7; ++j) sacc[i][j] = (floatx4){0.f, 0.f, 0.f, 0.f};
    {
        int k0 = l4 * 8;
        short8 aq[2];
        #pragma unroll
        for (int im = 0; im < 2; ++im)
            aq[im] = *(const short8*)(&sm.q[(mt[im] * 16 + l15) * HDIM + k0]);
        #pragma unroll
        for (int nt = 0; nt < 7; ++nt) {
            short8 bk = *(const short8*)(&sm.k[(nt * 16 + l15) * HDIM + k0]);
            #pragma unroll
            for (int im = 0; im < 2; ++im)
                sacc[im][nt] = __builtin_amdgcn_mfma_f32_16x16x32_bf16(
                    aq[im], bk, sacc[im][nt], 0, 0, 0);
        }
    }

    const float* biash = bias_pre ? (bias_pre + (size_t)h * NN2) : nullptr;
    const size_t moff = (size_t)(b & 63) * NN2;

    #pragma unroll
    for (int im = 0; im < 2; ++im)
        #pragma unroll
        for (int r = 0; r < 4; ++r) {
            int row = mt[im] * 16 + l4 * 4 + r;
            bool vrow = row < NTOK;
            float v[7];
            #pragma unroll
            for (int nt = 0; nt < 7; ++nt) {
                int j = nt * 16 + l15;
                bool vj = vrow && (j < NTOK);
                float bmv = 0.f;
                if (vj) {
                    float bias = biash ? biash[row * NTOK + j]
                        : rel_table[(size_t)rel_index[row * NTOK + j] * NHEAD + h];
                    bmv = bias + mask[moff + row * NTOK + j];
                }
                v[nt] = vj ? sacc[im][nt][r] * SCALE + bmv : -1e30f;
            }
            float mx = v[0];
            #pragma unroll
            for (int nt = 1; nt < 7; ++nt) mx = fmaxf(mx, v[nt]);
            #pragma unroll
            for (int off = 1; off < 16; off <<= 1) mx = fmaxf(mx, __shfl_xor(mx, off));
            float s = 0.f;
            #pragma unroll
            for (int nt = 0; nt < 7; ++nt) {
                float e = (v[nt] > -1e29f) ? __expf(v[nt] - mx) : 0.f;
                v[nt] = e;
                s += e;
            }
            #pragma unroll
            for (int off = 1; off < 16; off <<= 1) s += __shfl_xor(s, off);
            float inv = vrow ? 1.f / s : 0.f;
            #pragma unroll
            for (int nt = 0; nt < 7; ++nt)
                sm.u.P[row * 128 + nt * 16 + l15] = f2b(v[nt] * inv);
        }
    __syncthreads();

    floatx4 oacc[2][2];
    #pragma unroll
    for (int i = 0; i < 2; ++i)
        #pragma unroll
        for (int j = 0; j < 2; ++j) oacc[i][j] = (floatx4){0.f, 0.f, 0.f, 0.f};
    #pragma unroll
    for (int kt = 0; kt < 4; ++kt) {
        int kk = kt * 32 + l4 * 8;
        short8 ap[2];
        #pragma unroll
        for (int im = 0; im < 2; ++im)
            ap[im] = *(const short8*)(&sm.u.P[(mt[im] * 16 + l15) * 128 + kk]);
        #pragma unroll
        for (int nt = 0; nt < 2; ++nt) {
            short8 bv = *(const short8*)(&sm.vt[(nt * 16 + l15) * 128 + kk]);
            #pragma unroll
            for (int im = 0; im < 2; ++im)
                oacc[im][nt] = __builtin_amdgcn_mfma_f32_16x16x32_bf16(
                    ap[im], bv, oacc[im][nt], 0, 0, 0);
        }
    }
    float* ob = out + (size_t)b * NTOK * DIMX + h * HDIM;
    #pragma unroll
    for (int im = 0; im < 2; ++im)
        #pragma unroll
        for (int nt = 0; nt < 2; ++nt) {
            int dd = nt * 16 + l15;
            #pragma unroll
            for (int r = 0; r < 4; ++r) {
                int tok = mt[im] * 16 + l4 * 4 + r;
                if (tok < NTOK)
                    ob[(size_t)tok * DIMX + dd] = oacc[im][nt][r];
            }
        }
}

extern "C" void kernel_launch(void* const* d_in, const int* in_sizes, int n_in,
                              void* d_out, int out_size, void* d_ws, size_t ws_size,
                              hipStream_t stream) {
    const float* x = (const float*)d_in[0];
    const float* mask = (const float*)d_in[1];
    const float* qkv_w = (const float*)d_in[2];
    const float* qkv_b = (const float*)d_in[3];
    const float* rel_table = (const float*)d_in[4];
    const int* rel_index = (const int*)d_in[5];
    for (int i = 0; i < n_in; ++i) {
        switch (in_sizes[i]) {
            case 256 * NTOK * DIMX:  x         = (const float*)d_in[i]; break;
            case 64 * NN2:           mask      = (const float*)d_in[i]; break;
            case 3 * DIMX * DIMX:    qkv_w     = (const float*)d_in[i]; break;
            case 3 * DIMX:           qkv_b     = (const float*)d_in[i]; break;
            case 507 * NHEAD:        rel_table = (const float*)d_in[i]; break;
            case NN2:                rel_index = (const int*)d_in[i]; break;
            default: break;
        }
    }
    float* out = (float*)d_out;

    const size_t xb_bytes    = (size_t)BROWS * DIMX * 2;      // 38535168
    const size_t wb_bytes    = (size_t)NQKV * DIMX * 2;       // 3538944
    const size_t qkv_bytes   = (size_t)BROWS * NQKV * 2;      // 115605504
    const size_t bm_bytes    = (size_t)64 * NHEAD * BMSZ * 2; // 38535168
    const size_t biasA_bytes = (size_t)NHEAD * BMSZ * 4;      // 1204224
    const size_t total       = xb_bytes + wb_bytes + qkv_bytes;

    if (ws_size >= total + bm_bytes + biasA_bytes) {
        // preferred: two-stage bm (stage A in prep, stage B rides gemm)
        short* xb    = (short*)d_ws;
        short* wb    = (short*)((char*)d_ws + xb_bytes);
        short* qkv   = (short*)((char*)d_ws + xb_bytes + wb_bytes);
        short* bmp   = (short*)((char*)d_ws + total);
        float* biasA = (float*)((char*)d_ws + total + bm_bytes);

        prep_kernel<<<NB_X + NB_W + NB_BA, 256, 0, stream>>>(
            x, qkv_w, rel_table, rel_index, xb, wb, biasA);
        gemm_kernel<<<GEMM_BLKS + NB_B2, 256, 0, stream>>>(
            xb, wb, qkv_b, qkv, biasA, mask, bmp);
        attn_kernel7<<<256 * NHEAD, 256, 0, stream>>>(qkv, bmp, out);
    } else if (ws_size >= total) {
        // alias path: bm reuses xb region, serial full-gather after gemm
        short* xb  = (short*)d_ws;
        short* wb  = (short*)((char*)d_ws + xb_bytes);
        short* qkv = (short*)((char*)d_ws + xb_bytes + wb_bytes);
        short* bmp = (short*)d_ws;

        prep_kernel<<<NB_X + NB_W, 256, 0, stream>>>(
            x, qkv_w, rel_table, rel_index, xb, wb, nullptr);
        gemm_kernel<<<GEMM_BLKS, 256, 0, stream>>>(
            xb, wb, qkv_b, qkv, nullptr, mask, nullptr);
        int nbm = 64 * NHEAD * BMQ;
        bm_kernel<<<(nbm + 255) / 256, 256, 0, stream>>>(
            rel_table, rel_index, mask, bmp);
        attn_kernel7<<<256 * NHEAD, 256, 0, stream>>>(qkv, bmp, out);
    } else {
        const size_t bias_bytes = (size_t)NHEAD * NN2 * sizeof(float);
        float* bias_pre = (ws_size >= bias_bytes) ? (float*)d_ws : nullptr;
        if (bias_pre) {
            int nb = NHEAD * NN2;
            bias_gather_kernel<<<(nb + 255) / 256, 256, 0, stream>>>(rel_table, rel_index, bias_pre);
        }
        attn_fused<<<256 * NHEAD, 256, 0, stream>>>(x, mask, qkv_w, qkv_b,
                                                    bias_pre, rel_table, rel_index, out);
    }
}